// Round 1
// baseline (4131.036 us; speedup 1.0000x reference)
//
#include <hip/hip_runtime.h>

#define CAP 128

// ---- build bucket-CSR: count in-degree at dst, store src ids per dst ----
__global__ __launch_bounds__(256) void k_build(const int* __restrict__ esrc,
                                               const int* __restrict__ edst,
                                               int E, int* __restrict__ cnt,
                                               int* __restrict__ colbuf) {
    int e = blockIdx.x * 256 + threadIdx.x;
    if (e >= E) return;
    int d = edst[e];
    int s = esrc[e];
    int p = atomicAdd(&cnt[d], 1);
    if (p < CAP) colbuf[(size_t)d * CAP + p] = s;
}

// ---- dinv = rsqrt(in_degree + 1)  (self loop included) ----
__global__ __launch_bounds__(256) void k_dinv(const int* __restrict__ cnt,
                                              float* __restrict__ dinv, int n) {
    int i = blockIdx.x * 256 + threadIdx.x;
    if (i >= n) return;
    dinv[i] = rsqrtf((float)cnt[i] + 1.0f);
}

// ---- Y[n,M] = X[n,128] @ W[128,M], W staged in LDS, 8-row register blocking ----
template<int M>
__global__ __launch_bounds__(256) void k_gemm(const float* __restrict__ X,
                                              const float* __restrict__ W,
                                              float* __restrict__ Y, int n) {
    __shared__ float Ws[128 * M];
    for (int idx = threadIdx.x; idx < 128 * M / 4; idx += 256)
        ((float4*)Ws)[idx] = ((const float4*)W)[idx];
    __syncthreads();

    const int NG  = 256 / M;   // thread groups per block
    const int RPT = 64 / NG;   // rows per group
    int col  = threadIdx.x % M;
    int rg   = threadIdx.x / M;
    int grow = blockIdx.x * 64 + rg * RPT;

    for (int rb = 0; rb < RPT; rb += 8) {
        int rbase = grow + rb;
        float acc[8];
#pragma unroll
        for (int r = 0; r < 8; r++) acc[r] = 0.f;

        for (int k4 = 0; k4 < 128; k4 += 4) {
            float4 xv[8];
#pragma unroll
            for (int r = 0; r < 8; r++) {
                int row = rbase + r;
                xv[r] = (row < n) ? *(const float4*)&X[(size_t)row * 128 + k4]
                                  : make_float4(0.f, 0.f, 0.f, 0.f);
            }
#pragma unroll
            for (int kk = 0; kk < 4; kk++) {
                float w0 = Ws[(k4 + kk) * M + col];
#pragma unroll
                for (int r = 0; r < 8; r++) {
                    float xs = (kk == 0) ? xv[r].x : (kk == 1) ? xv[r].y
                             : (kk == 2) ? xv[r].z : xv[r].w;
                    acc[r] += xs * w0;
                }
            }
        }
#pragma unroll
        for (int r = 0; r < 8; r++) {
            int row = rbase + r;
            if (row < n) Y[(size_t)row * M + col] = acc[r];
        }
    }
}

// ---- per-node gather-aggregate: CH channels, float4 per lane ----
// out[i] = (bias + sum_{s in N(i)} H[s]*dinv[s]*dinv[i] + H[i]*dinv[i]^2) [relu]
template<int CH>
__global__ __launch_bounds__(256) void k_agg(const float* __restrict__ H,
                                             const int* __restrict__ cnt,
                                             const int* __restrict__ colbuf,
                                             const float* __restrict__ dinv,
                                             const float* __restrict__ bias,
                                             float* __restrict__ out,
                                             int n, int do_relu) {
    const int LPG = CH / 4;  // lanes per node group
    int t    = blockIdx.x * 256 + threadIdx.x;
    int gid  = t / LPG;
    int lane = t % LPG;
    if (gid >= n) return;

    float di = dinv[gid];
    int c = cnt[gid];
    if (c > CAP) c = CAP;

    const float4* Hv = (const float4*)H;
    float4 a = Hv[(size_t)gid * LPG + lane];
    float sw = di * di;
    float ax = a.x * sw, ay = a.y * sw, az = a.z * sw, aw = a.w * sw;

    const int* cb = colbuf + (size_t)gid * CAP;
    for (int j = 0; j < c; j++) {
        int s = cb[j];
        float w = dinv[s] * di;
        float4 h = Hv[(size_t)s * LPG + lane];
        ax += h.x * w; ay += h.y * w; az += h.z * w; aw += h.w * w;
    }

    float4 b = ((const float4*)bias)[lane];
    ax += b.x; ay += b.y; az += b.z; aw += b.w;
    if (do_relu) {
        ax = fmaxf(ax, 0.f); ay = fmaxf(ay, 0.f);
        az = fmaxf(az, 0.f); aw = fmaxf(aw, 0.f);
    }
    float4 o; o.x = ax; o.y = ay; o.z = az; o.w = aw;
    ((float4*)out)[(size_t)gid * LPG + lane] = o;
}

extern "C" void kernel_launch(void* const* d_in, const int* in_sizes, int n_in,
                              void* d_out, int out_size, void* d_ws, size_t ws_size,
                              hipStream_t stream) {
    const float* x  = (const float*)d_in[0];
    const int*   ei = (const int*)d_in[1];
    const float* W1 = (const float*)d_in[2];
    const float* b1 = (const float*)d_in[3];
    const float* W2 = (const float*)d_in[4];
    const float* b2 = (const float*)d_in[5];
    float* out = (float*)d_out;

    int N = in_sizes[0] / 128;
    int E = in_sizes[1] / 2;
    const int* esrc = ei;       // edge_index[0]
    const int* edst = ei + E;   // edge_index[1]

    char* ws = (char*)d_ws;
    size_t off = 0;
    auto alloc = [&](size_t bytes) -> void* {
        off = (off + 255) & ~(size_t)255;
        void* p = ws + off;
        off += bytes;
        return p;
    };
    int*   cnt    = (int*)  alloc((size_t)N * 4);
    float* dinv   = (float*)alloc((size_t)N * 4);
    int*   colbuf = (int*)  alloc((size_t)N * CAP * 4);
    float* hW1    = (float*)alloc((size_t)N * 128 * 4);
    float* x1     = (float*)alloc((size_t)N * 128 * 4);
    float* hW2    = hW1;  // hW1 dead after layer-1 aggregation; reuse

    hipMemsetAsync(cnt, 0, (size_t)N * 4, stream);
    k_build<<<(E + 255) / 256, 256, 0, stream>>>(esrc, edst, E, cnt, colbuf);
    k_dinv<<<(N + 255) / 256, 256, 0, stream>>>(cnt, dinv, N);

    // layer 1: hW1 = x @ W1 ; x1 = relu(aggregate(hW1) + b1)
    k_gemm<128><<<(N + 63) / 64, 256, 0, stream>>>(x, W1, hW1, N);
    k_agg<128><<<((size_t)N * 32 + 255) / 256, 256, 0, stream>>>(hW1, cnt, colbuf, dinv, b1, x1, N, 1);

    // layer 2: hW2 = x1 @ W2 ; out = aggregate(hW2) + b2
    k_gemm<64><<<(N + 63) / 64, 256, 0, stream>>>(x1, W2, hW2, N);
    k_agg<64><<<((size_t)N * 16 + 255) / 256, 256, 0, stream>>>(hW2, cnt, colbuf, dinv, b2, out, N, 0);
}

// Round 2
// 216.345 us; speedup vs baseline: 19.0947x; 19.0947x over previous
//
#include <hip/hip_runtime.h>

#define CAP 128

// ---- build bucket-CSR: count in-degree at dst, store src ids per dst ----
__global__ __launch_bounds__(256) void k_build(const int* __restrict__ esrc,
                                               const int* __restrict__ edst,
                                               int E, int* __restrict__ cnt,
                                               int* __restrict__ colbuf) {
    int e = blockIdx.x * 256 + threadIdx.x;
    if (e >= E) return;
    int d = edst[e];
    int s = esrc[e];
    int p = atomicAdd(&cnt[d], 1);
    if (p < CAP) colbuf[(size_t)d * CAP + p] = s;
}

// ---- dinv = rsqrt(in_degree + 1)  (self loop included) ----
__global__ __launch_bounds__(256) void k_dinv(const int* __restrict__ cnt,
                                              float* __restrict__ dinv, int n) {
    int i = blockIdx.x * 256 + threadIdx.x;
    if (i >= n) return;
    dinv[i] = rsqrtf((float)cnt[i] + 1.0f);
}

// ---- Y[n,M] = X[n,128] @ W[128,M] ----
// Block: 256 threads -> 64 rows x M cols tile. Thread: 4 rows x CPT cols.
// W staged in LDS (float4 reads); X float4 loads from global, 16-lane broadcast.
template<int M, int CPT>
__global__ __launch_bounds__(256) void k_gemm(const float* __restrict__ X,
                                              const float* __restrict__ W,
                                              float* __restrict__ Y, int n) {
    __shared__ float Ws[128 * M];
    for (int idx = threadIdx.x; idx < 128 * M / 4; idx += 256)
        ((float4*)Ws)[idx] = ((const float4*)W)[idx];
    __syncthreads();

    const int CG = M / CPT;       // col groups (16)
    int cg = threadIdx.x % CG;
    int rg = threadIdx.x / CG;    // 0..15
    int c0 = cg * CPT;
    int r0 = blockIdx.x * 64 + rg * 4;

    float acc[4][CPT];
#pragma unroll
    for (int i = 0; i < 4; i++)
#pragma unroll
        for (int j = 0; j < CPT; j++) acc[i][j] = 0.f;

    int rr[4];
#pragma unroll
    for (int i = 0; i < 4; i++) { int r = r0 + i; rr[i] = (r < n) ? r : (n - 1); }

    for (int k4 = 0; k4 < 128; k4 += 4) {
        float4 xv[4];
#pragma unroll
        for (int i = 0; i < 4; i++)
            xv[i] = *(const float4*)&X[(size_t)rr[i] * 128 + k4];
#pragma unroll
        for (int kk = 0; kk < 4; kk++) {
            float wv[CPT];
#pragma unroll
            for (int j = 0; j < CPT; j += 4) {
                float4 w4 = *(const float4*)&Ws[(k4 + kk) * M + c0 + j];
                wv[j] = w4.x; wv[j+1] = w4.y; wv[j+2] = w4.z; wv[j+3] = w4.w;
            }
#pragma unroll
            for (int i = 0; i < 4; i++) {
                float xs = (kk == 0) ? xv[i].x : (kk == 1) ? xv[i].y
                         : (kk == 2) ? xv[i].z : xv[i].w;
#pragma unroll
                for (int j = 0; j < CPT; j++) acc[i][j] += xs * wv[j];
            }
        }
    }

#pragma unroll
    for (int i = 0; i < 4; i++) {
        int r = r0 + i;
        if (r < n) {
#pragma unroll
            for (int j = 0; j < CPT; j += 4) {
                float4 o;
                o.x = acc[i][j]; o.y = acc[i][j+1]; o.z = acc[i][j+2]; o.w = acc[i][j+3];
                *(float4*)&Y[(size_t)r * M + c0 + j] = o;
            }
        }
    }
}

// ---- per-node gather-aggregate: CH channels, float4 per lane ----
// out[i] = (bias + sum_{s in N(i)} H[s]*dinv[s]*dinv[i] + H[i]*dinv[i]^2) [relu]
template<int CH>
__global__ __launch_bounds__(256) void k_agg(const float* __restrict__ H,
                                             const int* __restrict__ cnt,
                                             const int* __restrict__ colbuf,
                                             const float* __restrict__ dinv,
                                             const float* __restrict__ bias,
                                             float* __restrict__ out,
                                             int n, int do_relu) {
    const int LPG = CH / 4;  // lanes per node group
    int t    = blockIdx.x * 256 + threadIdx.x;
    int gid  = t / LPG;
    int lane = t % LPG;
    if (gid >= n) return;

    float di = dinv[gid];
    int c = cnt[gid];
    if (c > CAP) c = CAP;

    const float4* Hv = (const float4*)H;
    float4 a = Hv[(size_t)gid * LPG + lane];
    float sw = di * di;
    float ax = a.x * sw, ay = a.y * sw, az = a.z * sw, aw = a.w * sw;

    const int* cb = colbuf + (size_t)gid * CAP;
    for (int j = 0; j < c; j++) {
        int s = cb[j];
        float w = dinv[s] * di;
        float4 h = Hv[(size_t)s * LPG + lane];
        ax += h.x * w; ay += h.y * w; az += h.z * w; aw += h.w * w;
    }

    float4 b = ((const float4*)bias)[lane];
    ax += b.x; ay += b.y; az += b.z; aw += b.w;
    if (do_relu) {
        ax = fmaxf(ax, 0.f); ay = fmaxf(ay, 0.f);
        az = fmaxf(az, 0.f); aw = fmaxf(aw, 0.f);
    }
    float4 o; o.x = ax; o.y = ay; o.z = az; o.w = aw;
    ((float4*)out)[(size_t)gid * LPG + lane] = o;
}

extern "C" void kernel_launch(void* const* d_in, const int* in_sizes, int n_in,
                              void* d_out, int out_size, void* d_ws, size_t ws_size,
                              hipStream_t stream) {
    const float* x  = (const float*)d_in[0];
    const int*   ei = (const int*)d_in[1];
    const float* W1 = (const float*)d_in[2];
    const float* b1 = (const float*)d_in[3];
    const float* W2 = (const float*)d_in[4];
    const float* b2 = (const float*)d_in[5];
    float* out = (float*)d_out;

    int N = in_sizes[0] / 128;
    int E = in_sizes[1] / 2;
    const int* esrc = ei;       // edge_index[0]
    const int* edst = ei + E;   // edge_index[1]

    char* ws = (char*)d_ws;
    size_t off = 0;
    auto alloc = [&](size_t bytes) -> void* {
        off = (off + 255) & ~(size_t)255;
        void* p = ws + off;
        off += bytes;
        return p;
    };
    int*   cnt    = (int*)  alloc((size_t)N * 4);
    float* dinv   = (float*)alloc((size_t)N * 4);
    int*   colbuf = (int*)  alloc((size_t)N * CAP * 4);
    float* hW1    = (float*)alloc((size_t)N * 128 * 4);
    float* x1     = (float*)alloc((size_t)N * 128 * 4);
    float* hW2    = hW1;  // hW1 dead after layer-1 aggregation; reuse

    hipMemsetAsync(cnt, 0, (size_t)N * 4, stream);
    k_build<<<(E + 255) / 256, 256, 0, stream>>>(esrc, edst, E, cnt, colbuf);
    k_dinv<<<(N + 255) / 256, 256, 0, stream>>>(cnt, dinv, N);

    // layer 1: hW1 = x @ W1 ; x1 = relu(aggregate(hW1) + b1)
    k_gemm<128, 8><<<(N + 63) / 64, 256, 0, stream>>>(x, W1, hW1, N);
    k_agg<128><<<((size_t)N * 32 + 255) / 256, 256, 0, stream>>>(hW1, cnt, colbuf, dinv, b1, x1, N, 1);

    // layer 2: hW2 = x1 @ W2 ; out = aggregate(hW2) + b2
    k_gemm<64, 4><<<(N + 63) / 64, 256, 0, stream>>>(x1, W2, hW2, N);
    k_agg<64><<<((size_t)N * 16 + 255) / 256, 256, 0, stream>>>(hW2, cnt, colbuf, dinv, b2, out, N, 0);
}

// Round 3
// 207.444 us; speedup vs baseline: 19.9140x; 1.0429x over previous
//
#include <hip/hip_runtime.h>

#define CAP 128

// ---- build bucket-CSR: count in-degree at dst, store src ids per dst ----
__global__ __launch_bounds__(256) void k_build(const int* __restrict__ esrc,
                                               const int* __restrict__ edst,
                                               int E, int* __restrict__ cnt,
                                               int* __restrict__ colbuf) {
    int e = blockIdx.x * 256 + threadIdx.x;
    if (e >= E) return;
    int d = edst[e];
    int s = esrc[e];
    int p = atomicAdd(&cnt[d], 1);
    if (p < CAP) colbuf[(size_t)d * CAP + p] = s;
}

// ---- dinv = rsqrt(in_degree + 1)  (self loop included) ----
__global__ __launch_bounds__(256) void k_dinv(const int* __restrict__ cnt,
                                              float* __restrict__ dinv, int n) {
    int i = blockIdx.x * 256 + threadIdx.x;
    if (i >= n) return;
    dinv[i] = rsqrtf((float)cnt[i] + 1.0f);
}

// ---- Y[n,M] = X[n,128] @ W[128,M] ----
// Block: 256 threads -> 64 rows x M cols tile. Thread: 4 rows x CPT cols.
template<int M, int CPT>
__global__ __launch_bounds__(256) void k_gemm(const float* __restrict__ X,
                                              const float* __restrict__ W,
                                              float* __restrict__ Y, int n) {
    __shared__ float Ws[128 * M];
    for (int idx = threadIdx.x; idx < 128 * M / 4; idx += 256)
        ((float4*)Ws)[idx] = ((const float4*)W)[idx];
    __syncthreads();

    const int CG = M / CPT;       // col groups (16)
    int cg = threadIdx.x % CG;
    int rg = threadIdx.x / CG;    // 0..15
    int c0 = cg * CPT;
    int r0 = blockIdx.x * 64 + rg * 4;

    float acc[4][CPT];
#pragma unroll
    for (int i = 0; i < 4; i++)
#pragma unroll
        for (int j = 0; j < CPT; j++) acc[i][j] = 0.f;

    int rr[4];
#pragma unroll
    for (int i = 0; i < 4; i++) { int r = r0 + i; rr[i] = (r < n) ? r : (n - 1); }

    for (int k4 = 0; k4 < 128; k4 += 4) {
        float4 xv[4];
#pragma unroll
        for (int i = 0; i < 4; i++)
            xv[i] = *(const float4*)&X[(size_t)rr[i] * 128 + k4];
#pragma unroll
        for (int kk = 0; kk < 4; kk++) {
            float wv[CPT];
#pragma unroll
            for (int j = 0; j < CPT; j += 4) {
                float4 w4 = *(const float4*)&Ws[(k4 + kk) * M + c0 + j];
                wv[j] = w4.x; wv[j+1] = w4.y; wv[j+2] = w4.z; wv[j+3] = w4.w;
            }
#pragma unroll
            for (int i = 0; i < 4; i++) {
                float xs = (kk == 0) ? xv[i].x : (kk == 1) ? xv[i].y
                         : (kk == 2) ? xv[i].z : xv[i].w;
#pragma unroll
                for (int j = 0; j < CPT; j++) acc[i][j] += xs * wv[j];
            }
        }
    }

#pragma unroll
    for (int i = 0; i < 4; i++) {
        int r = r0 + i;
        if (r < n) {
#pragma unroll
            for (int j = 0; j < CPT; j += 4) {
                float4 o;
                o.x = acc[i][j]; o.y = acc[i][j+1]; o.z = acc[i][j+2]; o.w = acc[i][j+3];
                *(float4*)&Y[(size_t)r * M + c0 + j] = o;
            }
        }
    }
}

// ---- per-node gather-aggregate, 8-wide software-pipelined ----
// out[i] = bias + di*( sum_{s in N(i)} dinv[s]*H[s] + di*H[i] )   [relu]
template<int CH>
__global__ __launch_bounds__(256) void k_agg(const float* __restrict__ H,
                                             const int* __restrict__ cnt,
                                             const int* __restrict__ colbuf,
                                             const float* __restrict__ dinv,
                                             const float* __restrict__ bias,
                                             float* __restrict__ out,
                                             int n, int do_relu) {
    const int LPG = CH / 4;  // lanes per node group
    int t    = blockIdx.x * 256 + threadIdx.x;
    int gid  = t / LPG;
    int lane = t % LPG;
    if (gid >= n) return;

    float di = dinv[gid];
    int c = cnt[gid];
    if (c > CAP) c = CAP;

    const float4* Hv = (const float4*)H;
    float ax = 0.f, ay = 0.f, az = 0.f, aw = 0.f;

    const int* cb = colbuf + (size_t)gid * CAP;
    // batches of 8 with clamped masking: always full batches, no scalar tail.
    for (int j = 0; j < c; j += 8) {
        int s[8];
#pragma unroll
        for (int u = 0; u < 8; u++) {
            int jj = j + u;
            s[u] = cb[(jj < c) ? jj : (c - 1)];
        }
        float w[8];
#pragma unroll
        for (int u = 0; u < 8; u++)
            w[u] = (j + u < c) ? dinv[s[u]] : 0.f;
        float4 h[8];
#pragma unroll
        for (int u = 0; u < 8; u++)
            h[u] = Hv[(size_t)s[u] * LPG + lane];
#pragma unroll
        for (int u = 0; u < 8; u++) {
            ax += h[u].x * w[u];
            ay += h[u].y * w[u];
            az += h[u].z * w[u];
            aw += h[u].w * w[u];
        }
    }

    // self loop: weight di*di, then global scale by di
    float4 a = Hv[(size_t)gid * LPG + lane];
    float4 b = ((const float4*)bias)[lane];
    ax = (ax + di * a.x) * di + b.x;
    ay = (ay + di * a.y) * di + b.y;
    az = (az + di * a.z) * di + b.z;
    aw = (aw + di * a.w) * di + b.w;
    if (do_relu) {
        ax = fmaxf(ax, 0.f); ay = fmaxf(ay, 0.f);
        az = fmaxf(az, 0.f); aw = fmaxf(aw, 0.f);
    }
    float4 o; o.x = ax; o.y = ay; o.z = az; o.w = aw;
    ((float4*)out)[(size_t)gid * LPG + lane] = o;
}

extern "C" void kernel_launch(void* const* d_in, const int* in_sizes, int n_in,
                              void* d_out, int out_size, void* d_ws, size_t ws_size,
                              hipStream_t stream) {
    const float* x  = (const float*)d_in[0];
    const int*   ei = (const int*)d_in[1];
    const float* W1 = (const float*)d_in[2];
    const float* b1 = (const float*)d_in[3];
    const float* W2 = (const float*)d_in[4];
    const float* b2 = (const float*)d_in[5];
    float* out = (float*)d_out;

    int N = in_sizes[0] / 128;
    int E = in_sizes[1] / 2;
    const int* esrc = ei;       // edge_index[0]
    const int* edst = ei + E;   // edge_index[1]

    char* ws = (char*)d_ws;
    size_t off = 0;
    auto alloc = [&](size_t bytes) -> void* {
        off = (off + 255) & ~(size_t)255;
        void* p = ws + off;
        off += bytes;
        return p;
    };
    int*   cnt    = (int*)  alloc((size_t)N * 4);
    float* dinv   = (float*)alloc((size_t)N * 4);
    int*   colbuf = (int*)  alloc((size_t)N * CAP * 4);
    float* hW1    = (float*)alloc((size_t)N * 128 * 4);
    float* x1     = (float*)alloc((size_t)N * 128 * 4);
    float* hW2    = hW1;  // hW1 dead after layer-1 aggregation; reuse

    hipMemsetAsync(cnt, 0, (size_t)N * 4, stream);
    k_build<<<(E + 255) / 256, 256, 0, stream>>>(esrc, edst, E, cnt, colbuf);
    k_dinv<<<(N + 255) / 256, 256, 0, stream>>>(cnt, dinv, N);

    // layer 1: hW1 = x @ W1 ; x1 = relu(aggregate(hW1) + b1)
    k_gemm<128, 8><<<(N + 63) / 64, 256, 0, stream>>>(x, W1, hW1, N);
    k_agg<128><<<((size_t)N * 32 + 255) / 256, 256, 0, stream>>>(hW1, cnt, colbuf, dinv, b1, x1, N, 1);

    // layer 2: hW2 = x1 @ W2 ; out = aggregate(hW2) + b2
    k_gemm<64, 4><<<(N + 63) / 64, 256, 0, stream>>>(x1, W2, hW2, N);
    k_agg<64><<<((size_t)N * 16 + 255) / 256, 256, 0, stream>>>(hW2, cnt, colbuf, dinv, b2, out, N, 0);
}

// Round 4
// 173.444 us; speedup vs baseline: 23.8176x; 1.1960x over previous
//
#include <hip/hip_runtime.h>

#define CAP 128

typedef unsigned int uint;
typedef unsigned short ushort;

__device__ inline ushort f2bf(float f) {
    uint u = __float_as_uint(f);
    uint r = (u + 0x7fffu + ((u >> 16) & 1u)) >> 16;   // RNE
    return (ushort)r;
}
__device__ inline uint packbf2(float lo, float hi) {
    return (uint)f2bf(lo) | ((uint)f2bf(hi) << 16);
}
__device__ inline void unpackbf2(uint u, float& lo, float& hi) {
    lo = __uint_as_float(u << 16);
    hi = __uint_as_float(u & 0xffff0000u);
}

// ---- build bucket-CSR: count in-degree at dst, store src ids per dst ----
__global__ __launch_bounds__(256) void k_build(const int* __restrict__ esrc,
                                               const int* __restrict__ edst,
                                               int E, int* __restrict__ cnt,
                                               int* __restrict__ colbuf) {
    int e = blockIdx.x * 256 + threadIdx.x;
    if (e >= E) return;
    int d = edst[e];
    int s = esrc[e];
    int p = atomicAdd(&cnt[d], 1);
    if (p < CAP) colbuf[(size_t)d * CAP + p] = s;
}

// ---- dinv = rsqrt(in_degree + 1)  (self loop included) ----
__global__ __launch_bounds__(256) void k_dinv(const int* __restrict__ cnt,
                                              float* __restrict__ dinv, int n) {
    int i = blockIdx.x * 256 + threadIdx.x;
    if (i >= n) return;
    dinv[i] = rsqrtf((float)cnt[i] + 1.0f);
}

// ---- Yb[n,M](bf16) = X[n,128] @ W[128,M] ----
// Block: 256 threads -> 64 rows x M cols tile. Thread: 4 rows x CPT cols.
template<int M, int CPT>
__global__ __launch_bounds__(256) void k_gemm(const float* __restrict__ X,
                                              const float* __restrict__ W,
                                              ushort* __restrict__ Yb, int n) {
    __shared__ float Ws[128 * M];
    for (int idx = threadIdx.x; idx < 128 * M / 4; idx += 256)
        ((float4*)Ws)[idx] = ((const float4*)W)[idx];
    __syncthreads();

    const int CG = M / CPT;       // col groups (16)
    int cg = threadIdx.x % CG;
    int rg = threadIdx.x / CG;    // 0..15
    int c0 = cg * CPT;
    int r0 = blockIdx.x * 64 + rg * 4;

    float acc[4][CPT];
#pragma unroll
    for (int i = 0; i < 4; i++)
#pragma unroll
        for (int j = 0; j < CPT; j++) acc[i][j] = 0.f;

    int rr[4];
#pragma unroll
    for (int i = 0; i < 4; i++) { int r = r0 + i; rr[i] = (r < n) ? r : (n - 1); }

    for (int k4 = 0; k4 < 128; k4 += 4) {
        float4 xv[4];
#pragma unroll
        for (int i = 0; i < 4; i++)
            xv[i] = *(const float4*)&X[(size_t)rr[i] * 128 + k4];
#pragma unroll
        for (int kk = 0; kk < 4; kk++) {
            float wv[CPT];
#pragma unroll
            for (int j = 0; j < CPT; j += 4) {
                float4 w4 = *(const float4*)&Ws[(k4 + kk) * M + c0 + j];
                wv[j] = w4.x; wv[j+1] = w4.y; wv[j+2] = w4.z; wv[j+3] = w4.w;
            }
#pragma unroll
            for (int i = 0; i < 4; i++) {
                float xs = (kk == 0) ? xv[i].x : (kk == 1) ? xv[i].y
                         : (kk == 2) ? xv[i].z : xv[i].w;
#pragma unroll
                for (int j = 0; j < CPT; j++) acc[i][j] += xs * wv[j];
            }
        }
    }

#pragma unroll
    for (int i = 0; i < 4; i++) {
        int r = r0 + i;
        if (r < n) {
            uint up[CPT / 2];
#pragma unroll
            for (int j = 0; j < CPT; j += 2)
                up[j / 2] = packbf2(acc[i][j], acc[i][j + 1]);
            ushort* dst = Yb + (size_t)r * M + c0;
            if (CPT == 8)       *(uint4*)dst = *(uint4*)up;
            else if (CPT == 4)  *(uint2*)dst = *(uint2*)up;
        }
    }
}

// ---- per-node gather-aggregate from bf16 table, 8-wide pipelined ----
// out[i] = bias + di*( sum_{s in N(i)} dinv[s]*Hb[s] + di*Hb[i] )   [relu]
// Each lane covers 8 channels (16B bf16 load). LPG = CH/8 lanes per node.
template<int CH>
__global__ __launch_bounds__(256) void k_agg(const ushort* __restrict__ Hb,
                                             const int* __restrict__ cnt,
                                             const int* __restrict__ colbuf,
                                             const float* __restrict__ dinv,
                                             const float* __restrict__ bias,
                                             float* __restrict__ out,
                                             int n, int do_relu) {
    const int LPG = CH / 8;
    int t    = blockIdx.x * 256 + threadIdx.x;
    int gid  = t / LPG;
    int lane = t % LPG;
    if (gid >= n) return;

    float di = dinv[gid];
    int c = cnt[gid];
    if (c > CAP) c = CAP;

    float acc[8];
#pragma unroll
    for (int k = 0; k < 8; k++) acc[k] = 0.f;

    const int* cb = colbuf + (size_t)gid * CAP;
    for (int j = 0; j < c; j += 8) {
        int s[8];
#pragma unroll
        for (int u = 0; u < 8; u++) {
            int jj = j + u;
            s[u] = cb[(jj < c) ? jj : (c - 1)];
        }
        float w[8];
#pragma unroll
        for (int u = 0; u < 8; u++)
            w[u] = (j + u < c) ? dinv[s[u]] : 0.f;
        uint4 h[8];
#pragma unroll
        for (int u = 0; u < 8; u++)
            h[u] = *(const uint4*)(Hb + (size_t)s[u] * CH + lane * 8);
#pragma unroll
        for (int u = 0; u < 8; u++) {
            float f0, f1;
            unpackbf2(h[u].x, f0, f1); acc[0] += f0 * w[u]; acc[1] += f1 * w[u];
            unpackbf2(h[u].y, f0, f1); acc[2] += f0 * w[u]; acc[3] += f1 * w[u];
            unpackbf2(h[u].z, f0, f1); acc[4] += f0 * w[u]; acc[5] += f1 * w[u];
            unpackbf2(h[u].w, f0, f1); acc[6] += f0 * w[u]; acc[7] += f1 * w[u];
        }
    }

    // self loop (weight di), then global scale by di, then bias
    uint4 aself = *(const uint4*)(Hb + (size_t)gid * CH + lane * 8);
    float sf[8];
    unpackbf2(aself.x, sf[0], sf[1]);
    unpackbf2(aself.y, sf[2], sf[3]);
    unpackbf2(aself.z, sf[4], sf[5]);
    unpackbf2(aself.w, sf[6], sf[7]);

    float4 b0 = *(const float4*)&bias[lane * 8];
    float4 b1 = *(const float4*)&bias[lane * 8 + 4];
    float bb[8] = {b0.x, b0.y, b0.z, b0.w, b1.x, b1.y, b1.z, b1.w};

    float o[8];
#pragma unroll
    for (int k = 0; k < 8; k++) {
        float v = (acc[k] + di * sf[k]) * di + bb[k];
        o[k] = do_relu ? fmaxf(v, 0.f) : v;
    }
    float* dst = out + (size_t)gid * CH + lane * 8;
    *(float4*)dst       = make_float4(o[0], o[1], o[2], o[3]);
    *(float4*)(dst + 4) = make_float4(o[4], o[5], o[6], o[7]);
}

extern "C" void kernel_launch(void* const* d_in, const int* in_sizes, int n_in,
                              void* d_out, int out_size, void* d_ws, size_t ws_size,
                              hipStream_t stream) {
    const float* x  = (const float*)d_in[0];
    const int*   ei = (const int*)d_in[1];
    const float* W1 = (const float*)d_in[2];
    const float* b1 = (const float*)d_in[3];
    const float* W2 = (const float*)d_in[4];
    const float* b2 = (const float*)d_in[5];
    float* out = (float*)d_out;

    int N = in_sizes[0] / 128;
    int E = in_sizes[1] / 2;
    const int* esrc = ei;       // edge_index[0]
    const int* edst = ei + E;   // edge_index[1]

    char* ws = (char*)d_ws;
    size_t off = 0;
    auto alloc = [&](size_t bytes) -> void* {
        off = (off + 255) & ~(size_t)255;
        void* p = ws + off;
        off += bytes;
        return p;
    };
    int*    cnt    = (int*)   alloc((size_t)N * 4);
    float*  dinv   = (float*) alloc((size_t)N * 4);
    int*    colbuf = (int*)   alloc((size_t)N * CAP * 4);
    ushort* hW1b   = (ushort*)alloc((size_t)N * 128 * 2);   // bf16 table, layer 1
    float*  x1     = (float*) alloc((size_t)N * 128 * 4);
    ushort* hW2b   = hW1b;    // dead after layer-1 agg; reuse for layer-2 table

    hipMemsetAsync(cnt, 0, (size_t)N * 4, stream);
    k_build<<<(E + 255) / 256, 256, 0, stream>>>(esrc, edst, E, cnt, colbuf);
    k_dinv<<<(N + 255) / 256, 256, 0, stream>>>(cnt, dinv, N);

    // layer 1: hW1b = bf16(x @ W1) ; x1 = relu(aggregate(hW1b) + b1)
    k_gemm<128, 8><<<(N + 63) / 64, 256, 0, stream>>>(x, W1, hW1b, N);
    k_agg<128><<<((size_t)N * 16 + 255) / 256, 256, 0, stream>>>(hW1b, cnt, colbuf, dinv, b1, x1, N, 1);

    // layer 2: hW2b = bf16(x1 @ W2) ; out = aggregate(hW2b) + b2
    k_gemm<64, 4><<<(N + 63) / 64, 256, 0, stream>>>(x1, W2, hW2b, N);
    k_agg<64><<<((size_t)N * 8 + 255) / 256, 256, 0, stream>>>(hW2b, cnt, colbuf, dinv, b2, out, N, 0);
}